// Round 4
// baseline (3192.721 us; speedup 1.0000x reference)
//
#include <hip/hip_runtime.h>

// Only the temporal (LSTM) branch of the reference reaches the output
// (h_gcn is dead). Per node:
//   xt_s = x[n, 52+s] * W_tp + b_tp   (rank-1, folded into pre[] by precomp)
//   2-layer LSTM (H=32, T=12, torch gate order i,f,g,o)
//   out[n] = relu(h1 @ W_fc1 + b_fc1) @ W_fc2 + b_fc2
//
// Round-4 structure: 8 waves per 64-node group (512-thread blocks). Wave p
// computes gate rows [4p, 4p+4) -> j wave-uniform -> weights are SGPR
// scalar-broadcast loads. h exchanged across waves via LDS stride-33 rows
// (bank = (lane+c)%32, 2 lanes/bank = free). c-state is NAMED SCALARS via
// macro expansion — rounds 2/3 kept c in small arrays inside a jj-loop the
// compiler failed to unroll, demoting them to scratch (VGPR=84, WRITE 100MB,
// FETCH 430MB of spill traffic). No arrays with potentially-dynamic indices
// remain except h0/h1 (static indices only, proven register-resident in r1).

#define TSTEPS 12
#define ROWF 33   // LDS row stride (floats): (lane*33+c)%32=(lane+c)%32

__device__ __forceinline__ float fsig(float x) {
    float e = __expf(-x);
    return __builtin_amdgcn_rcpf(1.0f + e);
}

__device__ __forceinline__ float ftanh(float x) {
    float ax = fabsf(x);
    float e = __expf(-2.0f * ax);              // in (0,1], no overflow
    float r = (1.0f - e) * __builtin_amdgcn_rcpf(1.0f + e);
    return x < 0.0f ? -r : r;
}

// pre layout: [0:128) A0 (x coefficient per gate row), [128:256) C0 (bias),
// [256:384) C1 (layer-1 bias)
__global__ void precomp_kernel(const float* __restrict__ Wih0,
                               const float* __restrict__ Wtp,
                               const float* __restrict__ btp,
                               const float* __restrict__ bih0,
                               const float* __restrict__ bhh0,
                               const float* __restrict__ bih1,
                               const float* __restrict__ bhh1,
                               float* __restrict__ ws) {
    int r = threadIdx.x;   // 0..127
    if (r < 128) {
        float a = 0.0f, c = 0.0f;
#pragma unroll
        for (int k = 0; k < 16; ++k) {
            float w = Wih0[r * 16 + k];
            a += w * Wtp[k];
            c += w * btp[k];
        }
        ws[r]       = a;
        ws[128 + r] = c + bih0[r] + bhh0[r];
        ws[256 + r] = bih1[r] + bhh1[r];
    }
}

// Layer-0 row JJ (JJ is a literal 0..3). Reads h0[], updates CREG, writes
// new h into the LDS exchange row.
#define L0ROW(JJ, CREG) {                                                   \
    const int j0_ = jb + (JJ);                                              \
    float gi = pre[128 + j0_]      + xval * pre[j0_];                       \
    float gf = pre[128 + 32 + j0_] + xval * pre[32 + j0_];                  \
    float gg = pre[128 + 64 + j0_] + xval * pre[64 + j0_];                  \
    float go = pre[128 + 96 + j0_] + xval * pre[96 + j0_];                  \
    const float* w_ = Whh0 + j0_ * 32;                                      \
    _Pragma("unroll")                                                       \
    for (int k = 0; k < 32; ++k) {                                          \
        const float hk = h0[k];                                             \
        gi += w_[k]        * hk;                                            \
        gf += w_[1024 + k] * hk;                                            \
        gg += w_[2048 + k] * hk;                                            \
        go += w_[3072 + k] * hk;                                            \
    }                                                                       \
    const float cc_ = fsig(gf) * (CREG) + fsig(gi) * ftanh(gg);             \
    (CREG) = cc_;                                                           \
    myrow0[jb + (JJ)] = fsig(go) * ftanh(cc_);                              \
}

// Layer-1 row JJ. Reads h0[] (new) and h1[] (previous), updates CREG,
// writes new h into LDS exchange row.
#define L1ROW(JJ, CREG) {                                                   \
    const int j1_ = jb + (JJ);                                              \
    float gi = pre[256 + j1_];                                              \
    float gf = pre[256 + 32 + j1_];                                         \
    float gg = pre[256 + 64 + j1_];                                         \
    float go = pre[256 + 96 + j1_];                                         \
    const float* wi_ = Wih1 + j1_ * 32;                                     \
    const float* wh_ = Whh1 + j1_ * 32;                                     \
    _Pragma("unroll")                                                       \
    for (int k = 0; k < 32; ++k) {                                          \
        const float ak = h0[k];                                             \
        const float bk = h1[k];                                             \
        gi += wi_[k]        * ak + wh_[k]        * bk;                      \
        gf += wi_[1024 + k] * ak + wh_[1024 + k] * bk;                      \
        gg += wi_[2048 + k] * ak + wh_[2048 + k] * bk;                      \
        go += wi_[3072 + k] * ak + wh_[3072 + k] * bk;                      \
    }                                                                       \
    const float cc_ = fsig(gf) * (CREG) + fsig(gi) * ftanh(gg);             \
    (CREG) = cc_;                                                           \
    myrow1[jb + (JJ)] = fsig(go) * ftanh(cc_);                              \
}

__global__ __launch_bounds__(512, 2) void lstm_kernel(
    const float* __restrict__ x,
    const float* __restrict__ Whh0,   // [128,32]
    const float* __restrict__ Wih1,   // [128,32]
    const float* __restrict__ Whh1,   // [128,32]
    const float* __restrict__ Wfc1,   // [32,16]
    const float* __restrict__ bfc1,   // [16]
    const float* __restrict__ Wfc2,   // [16]
    const float* __restrict__ bfc2,   // [1]
    const float* __restrict__ pre,    // [384]
    float* __restrict__ out, int N)
{
    __shared__ float bufH0[64 * ROWF];   // 8.25 KB
    __shared__ float bufH1[64 * ROWF];   // 8.25 KB

    const int tid  = threadIdx.x;
    const int lane = tid & 63;
    const int p    = __builtin_amdgcn_readfirstlane(tid >> 6);  // 0..7
    const int jb   = p * 4;                    // this wave's gate-row base
    const int n    = blockIdx.x * 64 + lane;   // node (same set for all waves)
    const int nn   = (n < N) ? n : (N > 0 ? N - 1 : 0);
    const float* xr = x + (size_t)nn * 64 + 52;

    float h0[32], h1[32];
#pragma unroll
    for (int k = 0; k < 32; ++k) { h0[k] = 0.0f; h1[k] = 0.0f; }

    // c-state: named scalars (NOT arrays) — guaranteed register-resident
    float c00 = 0.0f, c01 = 0.0f, c02 = 0.0f, c03 = 0.0f;
    float c10 = 0.0f, c11 = 0.0f, c12 = 0.0f, c13 = 0.0f;

    float* myrow0 = &bufH0[lane * ROWF];
    float* myrow1 = &bufH1[lane * ROWF];

    float xval = xr[0];

#pragma unroll 1
    for (int t = 0; t < TSTEPS; ++t) {
        const float xnext = xr[(t < TSTEPS - 1) ? (t + 1) : (TSTEPS - 1)];

        // ----- layer 0: this wave's 4 rows -----
        L0ROW(0, c00) L0ROW(1, c01) L0ROW(2, c02) L0ROW(3, c03)
        __syncthreads();
#pragma unroll
        for (int q = 0; q < 32; ++q) h0[q] = myrow0[q];

        // ----- layer 1: this wave's 4 rows -----
        L1ROW(0, c10) L1ROW(1, c11) L1ROW(2, c12) L1ROW(3, c13)
        __syncthreads();
#pragma unroll
        for (int q = 0; q < 32; ++q) h1[q] = myrow1[q];
        // Safe single-buffered: wave A's next write to bufH0 (after this
        // barrier) cannot precede wave B's read of bufH0 (before it).

        xval = xnext;
    }

    // epilogue: relu(h1 @ Wfc1 + bfc1) @ Wfc2 + bfc2 — wave 0 only
    if (p == 0 && n < N) {
        float acc = bfc2[0];
#pragma unroll 1
        for (int m = 0; m < 16; ++m) {
            float a = bfc1[m];
#pragma unroll
            for (int k = 0; k < 32; ++k) a += h1[k] * Wfc1[k * 16 + m];
            acc += fmaxf(a, 0.0f) * Wfc2[m];
        }
        out[n] = acc;
    }
}

extern "C" void kernel_launch(void* const* d_in, const int* in_sizes, int n_in,
                              void* d_out, int out_size, void* d_ws, size_t ws_size,
                              hipStream_t stream) {
    (void)n_in; (void)out_size; (void)ws_size;
    const float* x    = (const float*)d_in[0];
    const float* Wtp  = (const float*)d_in[10];
    const float* btp  = (const float*)d_in[11];
    const float* Wih0 = (const float*)d_in[12];
    const float* Whh0 = (const float*)d_in[13];
    const float* bih0 = (const float*)d_in[14];
    const float* bhh0 = (const float*)d_in[15];
    const float* Wih1 = (const float*)d_in[16];
    const float* Whh1 = (const float*)d_in[17];
    const float* bih1 = (const float*)d_in[18];
    const float* bhh1 = (const float*)d_in[19];
    const float* Wfc1 = (const float*)d_in[20];
    const float* bfc1 = (const float*)d_in[21];
    const float* Wfc2 = (const float*)d_in[22];
    const float* bfc2 = (const float*)d_in[23];

    float* out = (float*)d_out;
    float* pre = (float*)d_ws;   // 384 floats

    const int N = in_sizes[0] / 64;

    precomp_kernel<<<1, 128, 0, stream>>>(Wih0, Wtp, btp, bih0, bhh0, bih1, bhh1, pre);

    const int nblocks = (N + 63) / 64;
    lstm_kernel<<<nblocks, 512, 0, stream>>>(
        x, Whh0, Wih1, Whh1, Wfc1, bfc1, Wfc2, bfc2, pre, out, N);
}

// Round 5
// 2659.956 us; speedup vs baseline: 1.2003x; 1.2003x over previous
//
#include <hip/hip_runtime.h>
#include <stdint.h>

// Only the temporal (LSTM) branch of the reference reaches the output
// (h_gcn is dead). Per node:
//   xt_s = x[n, 52+s] * W_tp + b_tp   (rank-1, folded into pre[] by precomp)
//   2-layer LSTM (H=32, T=12, torch gate order i,f,g,o)
//   out[n] = relu(h1 @ W_fc1 + b_fc1) @ W_fc2 + b_fc2
//
// Round-5 key fix: weights are read through CONSTANT ADDRESS SPACE (AS4)
// pointers with wave-uniform offsets -> guaranteed s_load scalarization.
// Rounds 1-4 all plateaued at ~1.7 ms because every weight went through a
// per-lane vector load (~2.3e8 VMEM wave-insts at ~4cyc/CU = ~1.5 ms of
// TA-pipe issue). On the scalar path the contiguous 32-float gate chunks
// merge into s_load_dwordx16 (~1.4e7 SMEM insts, negligible) and enter
// v_fmac_f32 as the SGPR operand — no VGPR, no VMEM.
//
// Geometry: 4 waves per 64-node block; wave p owns gate rows [8p,8p+8).
// h exchanged via LDS stride-33 rows (conflict-free, proven r3). c-state
// in named scalars (r4 fix). h0/h1 arrays static-indexed only.

#define TSTEPS 12
#define ROWF 33

typedef float __attribute__((address_space(4))) f_as4;
#define ASC(p) ((const f_as4*)(uint64_t)(const void*)(p))

__device__ __forceinline__ float fsig(float x) {
    float e = __expf(-x);
    return __builtin_amdgcn_rcpf(1.0f + e);
}

__device__ __forceinline__ float ftanh(float x) {
    float ax = fabsf(x);
    float e = __expf(-2.0f * ax);              // in (0,1], no overflow
    float r = (1.0f - e) * __builtin_amdgcn_rcpf(1.0f + e);
    return x < 0.0f ? -r : r;
}

// pre layout: [0:128) A0 (x coefficient per gate row), [128:256) C0 (bias),
// [256:384) C1 (layer-1 bias)
__global__ void precomp_kernel(const float* __restrict__ Wih0,
                               const float* __restrict__ Wtp,
                               const float* __restrict__ btp,
                               const float* __restrict__ bih0,
                               const float* __restrict__ bhh0,
                               const float* __restrict__ bih1,
                               const float* __restrict__ bhh1,
                               float* __restrict__ ws) {
    int r = threadIdx.x;   // 0..127
    if (r < 128) {
        float a = 0.0f, c = 0.0f;
#pragma unroll
        for (int k = 0; k < 16; ++k) {
            float w = Wih0[r * 16 + k];
            a += w * Wtp[k];
            c += w * btp[k];
        }
        ws[r]       = a;
        ws[128 + r] = c + bih0[r] + bhh0[r];
        ws[256 + r] = bih1[r] + bhh1[r];
    }
}

// Layer-0 row JJ (literal). Weight/bias reads all via AS4 (scalar path).
#define L0ROW(JJ, CREG) {                                                   \
    const int j0_ = jb + (JJ);                                              \
    float gi = prec[128 + j0_]      + xval * prec[j0_];                     \
    float gf = prec[128 + 32 + j0_] + xval * prec[32 + j0_];                \
    float gg = prec[128 + 64 + j0_] + xval * prec[64 + j0_];                \
    float go = prec[128 + 96 + j0_] + xval * prec[96 + j0_];                \
    const f_as4* w_ = Whh0c + j0_ * 32;                                     \
    _Pragma("unroll")                                                       \
    for (int k = 0; k < 32; ++k) {                                          \
        const float hk = h0[k];                                             \
        gi += w_[k]        * hk;                                            \
        gf += w_[1024 + k] * hk;                                            \
        gg += w_[2048 + k] * hk;                                            \
        go += w_[3072 + k] * hk;                                            \
    }                                                                       \
    const float cc_ = fsig(gf) * (CREG) + fsig(gi) * ftanh(gg);             \
    (CREG) = cc_;                                                           \
    myrow0[jb + (JJ)] = fsig(go) * ftanh(cc_);                              \
}

#define L1ROW(JJ, CREG) {                                                   \
    const int j1_ = jb + (JJ);                                              \
    float gi = prec[256 + j1_];                                             \
    float gf = prec[256 + 32 + j1_];                                        \
    float gg = prec[256 + 64 + j1_];                                        \
    float go = prec[256 + 96 + j1_];                                        \
    const f_as4* wi_ = Wih1c + j1_ * 32;                                    \
    const f_as4* wh_ = Whh1c + j1_ * 32;                                    \
    _Pragma("unroll")                                                       \
    for (int k = 0; k < 32; ++k) {                                          \
        const float ak = h0[k];                                             \
        const float bk = h1[k];                                             \
        gi += wi_[k]        * ak + wh_[k]        * bk;                      \
        gf += wi_[1024 + k] * ak + wh_[1024 + k] * bk;                      \
        gg += wi_[2048 + k] * ak + wh_[2048 + k] * bk;                      \
        go += wi_[3072 + k] * ak + wh_[3072 + k] * bk;                      \
    }                                                                       \
    const float cc_ = fsig(gf) * (CREG) + fsig(gi) * ftanh(gg);             \
    (CREG) = cc_;                                                           \
    myrow1[jb + (JJ)] = fsig(go) * ftanh(cc_);                              \
}

__global__ __launch_bounds__(256, 4) void lstm_kernel(
    const float* __restrict__ x,
    const float* __restrict__ Whh0,   // [128,32]
    const float* __restrict__ Wih1,   // [128,32]
    const float* __restrict__ Whh1,   // [128,32]
    const float* __restrict__ Wfc1,   // [32,16]
    const float* __restrict__ bfc1,   // [16]
    const float* __restrict__ Wfc2,   // [16]
    const float* __restrict__ bfc2,   // [1]
    const float* __restrict__ pre,    // [384]
    float* __restrict__ out, int N)
{
    __shared__ float bufH0[64 * ROWF];   // 8.25 KB
    __shared__ float bufH1[64 * ROWF];   // 8.25 KB

    // Constant-address-space views: uniform offsets -> s_load guaranteed.
    const f_as4* Whh0c = ASC(Whh0);
    const f_as4* Wih1c = ASC(Wih1);
    const f_as4* Whh1c = ASC(Whh1);
    const f_as4* prec  = ASC(pre);

    const int tid  = threadIdx.x;
    const int lane = tid & 63;
    const int p    = __builtin_amdgcn_readfirstlane(tid >> 6);  // 0..3
    const int jb   = p * 8;                    // this wave's gate-row base
    const int n    = blockIdx.x * 64 + lane;   // node (same set for all waves)
    const int nn   = (n < N) ? n : (N > 0 ? N - 1 : 0);
    const float* xr = x + (size_t)nn * 64 + 52;

    float h0[32], h1[32];
#pragma unroll
    for (int k = 0; k < 32; ++k) { h0[k] = 0.0f; h1[k] = 0.0f; }

    // c-state: named scalars — guaranteed register-resident (r4 lesson)
    float c00 = 0.0f, c01 = 0.0f, c02 = 0.0f, c03 = 0.0f;
    float c04 = 0.0f, c05 = 0.0f, c06 = 0.0f, c07 = 0.0f;
    float c10 = 0.0f, c11 = 0.0f, c12 = 0.0f, c13 = 0.0f;
    float c14 = 0.0f, c15 = 0.0f, c16 = 0.0f, c17 = 0.0f;

    float* myrow0 = &bufH0[lane * ROWF];
    float* myrow1 = &bufH1[lane * ROWF];

#pragma unroll 1
    for (int t = 0; t < TSTEPS; ++t) {
        const float xval = xr[t];

        // ----- layer 0: this wave's 8 rows -----
        L0ROW(0, c00) L0ROW(1, c01) L0ROW(2, c02) L0ROW(3, c03)
        L0ROW(4, c04) L0ROW(5, c05) L0ROW(6, c06) L0ROW(7, c07)
        __syncthreads();
#pragma unroll
        for (int q = 0; q < 32; ++q) h0[q] = myrow0[q];

        // ----- layer 1: this wave's 8 rows -----
        L1ROW(0, c10) L1ROW(1, c11) L1ROW(2, c12) L1ROW(3, c13)
        L1ROW(4, c14) L1ROW(5, c15) L1ROW(6, c16) L1ROW(7, c17)
        __syncthreads();
#pragma unroll
        for (int q = 0; q < 32; ++q) h1[q] = myrow1[q];
        // Single-buffered is safe: next write to bufH0 happens only after
        // the layer-1 barrier of this step; reads of bufH0 precede it.
    }

    // epilogue: relu(h1 @ Wfc1 + bfc1) @ Wfc2 + bfc2 — wave 0 only
    if (p == 0 && n < N) {
        const f_as4* Wfc1c = ASC(Wfc1);
        const f_as4* bfc1c = ASC(bfc1);
        const f_as4* Wfc2c = ASC(Wfc2);
        const f_as4* bfc2c = ASC(bfc2);
        float acc = bfc2c[0];
#pragma unroll 1
        for (int m = 0; m < 16; ++m) {
            float a = bfc1c[m];
#pragma unroll
            for (int k = 0; k < 32; ++k) a += h1[k] * Wfc1c[k * 16 + m];
            acc += fmaxf(a, 0.0f) * Wfc2c[m];
        }
        out[n] = acc;
    }
}

extern "C" void kernel_launch(void* const* d_in, const int* in_sizes, int n_in,
                              void* d_out, int out_size, void* d_ws, size_t ws_size,
                              hipStream_t stream) {
    (void)n_in; (void)out_size; (void)ws_size;
    const float* x    = (const float*)d_in[0];
    const float* Wtp  = (const float*)d_in[10];
    const float* btp  = (const float*)d_in[11];
    const float* Wih0 = (const float*)d_in[12];
    const float* Whh0 = (const float*)d_in[13];
    const float* bih0 = (const float*)d_in[14];
    const float* bhh0 = (const float*)d_in[15];
    const float* Wih1 = (const float*)d_in[16];
    const float* Whh1 = (const float*)d_in[17];
    const float* bih1 = (const float*)d_in[18];
    const float* bhh1 = (const float*)d_in[19];
    const float* Wfc1 = (const float*)d_in[20];
    const float* bfc1 = (const float*)d_in[21];
    const float* Wfc2 = (const float*)d_in[22];
    const float* bfc2 = (const float*)d_in[23];

    float* out = (float*)d_out;
    float* pre = (float*)d_ws;   // 384 floats

    const int N = in_sizes[0] / 64;

    precomp_kernel<<<1, 128, 0, stream>>>(Wih0, Wtp, btp, bih0, bhh0, bih1, bhh1, pre);

    const int nblocks = (N + 63) / 64;
    lstm_kernel<<<nblocks, 256, 0, stream>>>(
        x, Whh0, Wih1, Whh1, Wfc1, bfc1, Wfc2, bfc2, pre, out, N);
}

// Round 6
// 2517.907 us; speedup vs baseline: 1.2680x; 1.0564x over previous
//
#include <hip/hip_runtime.h>
#include <stdint.h>

// Only the temporal (LSTM) branch of the reference reaches the output
// (h_gcn is dead). Per node:
//   xt_s = x[n, 52+s] * W_tp + b_tp   (rank-1, folded into pre[] by precomp)
//   2-layer LSTM (H=32, T=12, torch gate order i,f,g,o)
//   out[n] = relu(h1 @ W_fc1 + b_fc1) @ W_fc2 + b_fc2
//
// Structure (r5): weights via CONSTANT ADDRESS SPACE (AS4) pointers with
// wave-uniform offsets -> s_load_dwordx16 scalar broadcast, FMAs take the
// weight as SGPR operand (no VMEM, no VGPR). 4 waves per 64-node block;
// wave p owns gate rows [8p,8p+8). h exchanged via LDS stride-33 rows
// (conflict-free). c-state in named scalars.
//
// Round-6 fix: amdgpu_waves_per_eu(4,4) — exact occupancy. r5's allocator
// targeted 8 waves/EU (VGPR_Count=64) and spilled ~50 VGPRs of h-state to
// scratch (FETCH 1.58 GB, WRITE 1.18 GB, HBM-bound at 1080 GB/s).
// launch_bounds' 2nd arg is only a FLOOR (budget<=128); setting max=4 too
// pins the RA budget at 128 VGPRs >= ~110 live -> zero spill.

#define TSTEPS 12
#define ROWF 33

typedef float __attribute__((address_space(4))) f_as4;
#define ASC(p) ((const f_as4*)(uint64_t)(const void*)(p))

__device__ __forceinline__ float fsig(float x) {
    float e = __expf(-x);
    return __builtin_amdgcn_rcpf(1.0f + e);
}

__device__ __forceinline__ float ftanh(float x) {
    float ax = fabsf(x);
    float e = __expf(-2.0f * ax);              // in (0,1], no overflow
    float r = (1.0f - e) * __builtin_amdgcn_rcpf(1.0f + e);
    return x < 0.0f ? -r : r;
}

// pre layout: [0:128) A0 (x coefficient per gate row), [128:256) C0 (bias),
// [256:384) C1 (layer-1 bias)
__global__ void precomp_kernel(const float* __restrict__ Wih0,
                               const float* __restrict__ Wtp,
                               const float* __restrict__ btp,
                               const float* __restrict__ bih0,
                               const float* __restrict__ bhh0,
                               const float* __restrict__ bih1,
                               const float* __restrict__ bhh1,
                               float* __restrict__ ws) {
    int r = threadIdx.x;   // 0..127
    if (r < 128) {
        float a = 0.0f, c = 0.0f;
#pragma unroll
        for (int k = 0; k < 16; ++k) {
            float w = Wih0[r * 16 + k];
            a += w * Wtp[k];
            c += w * btp[k];
        }
        ws[r]       = a;
        ws[128 + r] = c + bih0[r] + bhh0[r];
        ws[256 + r] = bih1[r] + bhh1[r];
    }
}

// Layer-0 row JJ (literal). Weight/bias reads all via AS4 (scalar path).
#define L0ROW(JJ, CREG) {                                                   \
    const int j0_ = jb + (JJ);                                              \
    float gi = prec[128 + j0_]      + xval * prec[j0_];                     \
    float gf = prec[128 + 32 + j0_] + xval * prec[32 + j0_];                \
    float gg = prec[128 + 64 + j0_] + xval * prec[64 + j0_];                \
    float go = prec[128 + 96 + j0_] + xval * prec[96 + j0_];                \
    const f_as4* w_ = Whh0c + j0_ * 32;                                     \
    _Pragma("unroll")                                                       \
    for (int k = 0; k < 32; ++k) {                                          \
        const float hk = h0[k];                                             \
        gi += w_[k]        * hk;                                            \
        gf += w_[1024 + k] * hk;                                            \
        gg += w_[2048 + k] * hk;                                            \
        go += w_[3072 + k] * hk;                                            \
    }                                                                       \
    const float cc_ = fsig(gf) * (CREG) + fsig(gi) * ftanh(gg);             \
    (CREG) = cc_;                                                           \
    myrow0[jb + (JJ)] = fsig(go) * ftanh(cc_);                              \
}

#define L1ROW(JJ, CREG) {                                                   \
    const int j1_ = jb + (JJ);                                              \
    float gi = prec[256 + j1_];                                             \
    float gf = prec[256 + 32 + j1_];                                        \
    float gg = prec[256 + 64 + j1_];                                        \
    float go = prec[256 + 96 + j1_];                                        \
    const f_as4* wi_ = Wih1c + j1_ * 32;                                    \
    const f_as4* wh_ = Whh1c + j1_ * 32;                                    \
    _Pragma("unroll")                                                       \
    for (int k = 0; k < 32; ++k) {                                          \
        const float ak = h0[k];                                             \
        const float bk = h1[k];                                             \
        gi += wi_[k]        * ak + wh_[k]        * bk;                      \
        gf += wi_[1024 + k] * ak + wh_[1024 + k] * bk;                      \
        gg += wi_[2048 + k] * ak + wh_[2048 + k] * bk;                      \
        go += wi_[3072 + k] * ak + wh_[3072 + k] * bk;                      \
    }                                                                       \
    const float cc_ = fsig(gf) * (CREG) + fsig(gi) * ftanh(gg);             \
    (CREG) = cc_;                                                           \
    myrow1[jb + (JJ)] = fsig(go) * ftanh(cc_);                              \
}

__global__ __launch_bounds__(256)
__attribute__((amdgpu_waves_per_eu(4, 4)))
void lstm_kernel(
    const float* __restrict__ x,
    const float* __restrict__ Whh0,   // [128,32]
    const float* __restrict__ Wih1,   // [128,32]
    const float* __restrict__ Whh1,   // [128,32]
    const float* __restrict__ Wfc1,   // [32,16]
    const float* __restrict__ bfc1,   // [16]
    const float* __restrict__ Wfc2,   // [16]
    const float* __restrict__ bfc2,   // [1]
    const float* __restrict__ pre,    // [384]
    float* __restrict__ out, int N)
{
    __shared__ float bufH0[64 * ROWF];   // 8.25 KB
    __shared__ float bufH1[64 * ROWF];   // 8.25 KB

    // Constant-address-space views: uniform offsets -> s_load guaranteed.
    const f_as4* Whh0c = ASC(Whh0);
    const f_as4* Wih1c = ASC(Wih1);
    const f_as4* Whh1c = ASC(Whh1);
    const f_as4* prec  = ASC(pre);

    const int tid  = threadIdx.x;
    const int lane = tid & 63;
    const int p    = __builtin_amdgcn_readfirstlane(tid >> 6);  // 0..3
    const int jb   = p * 8;                    // this wave's gate-row base
    const int n    = blockIdx.x * 64 + lane;   // node (same set for all waves)
    const int nn   = (n < N) ? n : (N > 0 ? N - 1 : 0);
    const float* xr = x + (size_t)nn * 64 + 52;

    float h0[32], h1[32];
#pragma unroll
    for (int k = 0; k < 32; ++k) { h0[k] = 0.0f; h1[k] = 0.0f; }

    // c-state: named scalars — guaranteed register-resident (r4 lesson)
    float c00 = 0.0f, c01 = 0.0f, c02 = 0.0f, c03 = 0.0f;
    float c04 = 0.0f, c05 = 0.0f, c06 = 0.0f, c07 = 0.0f;
    float c10 = 0.0f, c11 = 0.0f, c12 = 0.0f, c13 = 0.0f;
    float c14 = 0.0f, c15 = 0.0f, c16 = 0.0f, c17 = 0.0f;

    float* myrow0 = &bufH0[lane * ROWF];
    float* myrow1 = &bufH1[lane * ROWF];

#pragma unroll 1
    for (int t = 0; t < TSTEPS; ++t) {
        const float xval = xr[t];

        // ----- layer 0: this wave's 8 rows -----
        L0ROW(0, c00) L0ROW(1, c01) L0ROW(2, c02) L0ROW(3, c03)
        L0ROW(4, c04) L0ROW(5, c05) L0ROW(6, c06) L0ROW(7, c07)
        __syncthreads();
#pragma unroll
        for (int q = 0; q < 32; ++q) h0[q] = myrow0[q];

        // ----- layer 1: this wave's 8 rows -----
        L1ROW(0, c10) L1ROW(1, c11) L1ROW(2, c12) L1ROW(3, c13)
        L1ROW(4, c14) L1ROW(5, c15) L1ROW(6, c16) L1ROW(7, c17)
        __syncthreads();
#pragma unroll
        for (int q = 0; q < 32; ++q) h1[q] = myrow1[q];
        // Single-buffered is safe: next write to bufH0 happens only after
        // the layer-1 barrier of this step; reads of bufH0 precede it.
    }

    // epilogue: relu(h1 @ Wfc1 + bfc1) @ Wfc2 + bfc2 — wave 0 only
    if (p == 0 && n < N) {
        const f_as4* Wfc1c = ASC(Wfc1);
        const f_as4* bfc1c = ASC(bfc1);
        const f_as4* Wfc2c = ASC(Wfc2);
        const f_as4* bfc2c = ASC(bfc2);
        float acc = bfc2c[0];
#pragma unroll 1
        for (int m = 0; m < 16; ++m) {
            float a = bfc1c[m];
#pragma unroll
            for (int k = 0; k < 32; ++k) a += h1[k] * Wfc1c[k * 16 + m];
            acc += fmaxf(a, 0.0f) * Wfc2c[m];
        }
        out[n] = acc;
    }
}

extern "C" void kernel_launch(void* const* d_in, const int* in_sizes, int n_in,
                              void* d_out, int out_size, void* d_ws, size_t ws_size,
                              hipStream_t stream) {
    (void)n_in; (void)out_size; (void)ws_size;
    const float* x    = (const float*)d_in[0];
    const float* Wtp  = (const float*)d_in[10];
    const float* btp  = (const float*)d_in[11];
    const float* Wih0 = (const float*)d_in[12];
    const float* Whh0 = (const float*)d_in[13];
    const float* bih0 = (const float*)d_in[14];
    const float* bhh0 = (const float*)d_in[15];
    const float* Wih1 = (const float*)d_in[16];
    const float* Whh1 = (const float*)d_in[17];
    const float* bih1 = (const float*)d_in[18];
    const float* bhh1 = (const float*)d_in[19];
    const float* Wfc1 = (const float*)d_in[20];
    const float* bfc1 = (const float*)d_in[21];
    const float* Wfc2 = (const float*)d_in[22];
    const float* bfc2 = (const float*)d_in[23];

    float* out = (float*)d_out;
    float* pre = (float*)d_ws;   // 384 floats

    const int N = in_sizes[0] / 64;

    precomp_kernel<<<1, 128, 0, stream>>>(Wih0, Wtp, btp, bih0, bhh0, bih1, bhh1, pre);

    const int nblocks = (N + 63) / 64;
    lstm_kernel<<<nblocks, 256, 0, stream>>>(
        x, Whh0, Wih1, Whh1, Wfc1, bfc1, Wfc2, bfc2, pre, out, N);
}